// Round 9
// baseline (174.792 us; speedup 1.0000x reference)
//
#include <hip/hip_runtime.h>
#include <math.h>

#define NPIX 1089
#define DIM 512
#define NIMG 16
#define NLBL 8      // labels 0..6 used, 7 = padding bucket
#define NMASK 6
#define INVT 14.2857142857142857f  // 1/0.07

#define NGRP 72     // 16-row groups per image (72*16 = 1152 padded rows)
#define NROWPAD 1152
#define NT9 9       // 128-row tiles per dim

// Embeddings are unit-normalized by the module, so rn2 == 1 (+-2e-7):
// max-subtract constant, q_l (= cnt_l), totq (= NPIX) collapse.
//
// bfemb fragment-ordered layout (uint4 units):
//   index = ((img*NGRP + g)*16 + kc)*64 + (q*16 + m),  row = g*16+m, hw = kc*32 + q*8
// => any MFMA A/B fragment load is ONE contiguous 1KB wave load.
//
// E9[img][s][1152]: 9 owner-slots per image; each (rowgroup,slot) written by
// exactly ONE epass block (plain stores, no memset, no atomics).
//
// Ticket choreography (device-scope atomics + __threadfence, per G16):
//   packsum block(0,0) zeroes counters[0..16] (16 per-image + 1 global).
//   Each epass block: stores E9, fence, barrier, tid0 ticket++ on its image.
//   45th block per image runs the per-image loss tail (overlapped with other
//   images' epass blocks), writes per_img[b], fence, global ticket++; the
//   16th winner aggregates into out[0].

typedef short v8s __attribute__((ext_vector_type(8)));
typedef float v4f __attribute__((ext_vector_type(4)));

__device__ __forceinline__ float wave_reduce(float x) {
#pragma unroll
  for (int o = 32; o > 0; o >>= 1) x += __shfl_xor(x, o, 64);
  return x;
}
__device__ __forceinline__ unsigned bfbits(float x) {  // fp32 -> bf16 bits, RNE
  unsigned u = __float_as_uint(x);
  return (u + 0x7FFFu + ((u >> 16) & 1u)) >> 16;
}
__device__ __forceinline__ unsigned pk(float lo, float hi) {
  return bfbits(lo) | (bfbits(hi) << 16);
}

// -------- K1: fused labels + pack (fp32 -> fragment-ordered bf16) + partial sums ----
// Grid (18, NIMG): blockIdx.x = g9*2 + dh. Block 512 = 8 row-streams x 64 dim-lanes.
// dh==0 blocks also export labels[] and per-group label counts cnt9[] so the
// loss tail never touches masks again.
__global__ __launch_bounds__(512) void k_packsum(const float* __restrict__ emb,
                                                 const float* __restrict__ masks,
                                                 uint2* __restrict__ bfemb2,
                                                 float* __restrict__ sums9,
                                                 int* __restrict__ labels,
                                                 float* __restrict__ cnt9,
                                                 unsigned* __restrict__ counters) {
  int b = blockIdx.y;
  int g9 = blockIdx.x >> 1, dh = blockIdx.x & 1;  // 128-row group, 256-dim half
  int tid = threadIdx.x, dd = tid & 63, w4 = tid >> 6, lane = tid & 63;
  __shared__ float msum[NMASK];
  __shared__ int slab[128];
  __shared__ int scnt[NLBL];
  __shared__ float4 red[8 * 8 * 64];  // [l][w4][dd], 64 KB
  if (tid < NMASK) msum[tid] = 0.f;
  if (tid < NLBL) scnt[tid] = 0;
  if (b == 0 && blockIdx.x == 0 && tid < 17) counters[tid] = 0u;  // tickets
  __syncthreads();
  // per-channel mask sums (active test)
  {
    float am[NMASK] = {0.f, 0.f, 0.f, 0.f, 0.f, 0.f};
    for (int p = tid; p < NPIX; p += 512) {
#pragma unroll
      for (int c = 0; c < NMASK; c++) am[c] += masks[((size_t)b * NMASK + c) * NPIX + p];
    }
#pragma unroll
    for (int c = 0; c < NMASK; c++) {
      float v = wave_reduce(am[c]);
      if (lane == 0) atomicAdd(&msum[c], v);
    }
  }
  __syncthreads();
  if (tid < 128) {
    int r = g9 * 128 + tid;
    int lab = 7;
    if (r < NPIX) {
      lab = 0;
#pragma unroll
      for (int c = 0; c < NMASK; c++) {
        float mv = masks[((size_t)b * NMASK + c) * NPIX + r];
        if (mv > 0.5f && msum[c] > 0.f) lab = c + 1;  // ascending overwrite == max over hits
      }
    }
    slab[tid] = lab;
    if (dh == 0) {
      labels[b * NROWPAD + r] = lab;
      if (r < NPIX) atomicAdd(&scnt[lab], 1);   // exclude pad rows
    }
  }
  __syncthreads();
  if (dh == 0 && tid < NLBL) cnt9[((size_t)b * NT9 + g9) * NLBL + tid] = (float)scnt[tid];
  float4 fa0 = {0,0,0,0}, fa1 = {0,0,0,0}, fa2 = {0,0,0,0}, fa3 = {0,0,0,0};
  float4 fa4 = {0,0,0,0}, fa5 = {0,0,0,0}, fa6 = {0,0,0,0}, fa7 = {0,0,0,0};
  int kc = dh * 8 + (dd >> 3), q = (dd >> 1) & 3, half = dd & 1;
#pragma unroll
  for (int k = 0; k < 16; k++) {
    int r = g9 * 128 + w4 + k * 8;           // wave-uniform row
    bool v = r < NPIX;
    int rc = v ? r : (NPIX - 1);
    float4 x = ((const float4*)(emb + (size_t)(b * NPIX + rc) * DIM))[dh * 64 + dd];
    if (!v) x = make_float4(0.f, 0.f, 0.f, 0.f);
    uint2 o = make_uint2(pk(x.x, x.y), pk(x.z, x.w));
    bfemb2[((((size_t)(b * NGRP + (r >> 4)) * 16 + kc) * 64) + q * 16 + (r & 15)) * 2 + half] = o;
    int lab = __builtin_amdgcn_readfirstlane(slab[r - g9 * 128]);
    switch (lab) {
      case 0: fa0.x += x.x; fa0.y += x.y; fa0.z += x.z; fa0.w += x.w; break;
      case 1: fa1.x += x.x; fa1.y += x.y; fa1.z += x.z; fa1.w += x.w; break;
      case 2: fa2.x += x.x; fa2.y += x.y; fa2.z += x.z; fa2.w += x.w; break;
      case 3: fa3.x += x.x; fa3.y += x.y; fa3.z += x.z; fa3.w += x.w; break;
      case 4: fa4.x += x.x; fa4.y += x.y; fa4.z += x.z; fa4.w += x.w; break;
      case 5: fa5.x += x.x; fa5.y += x.y; fa5.z += x.z; fa5.w += x.w; break;
      case 6: fa6.x += x.x; fa6.y += x.y; fa6.z += x.z; fa6.w += x.w; break;
      default: fa7.x += x.x; fa7.y += x.y; fa7.z += x.z; fa7.w += x.w; break;
    }
  }
  red[(0 * 8 + w4) * 64 + dd] = fa0; red[(1 * 8 + w4) * 64 + dd] = fa1;
  red[(2 * 8 + w4) * 64 + dd] = fa2; red[(3 * 8 + w4) * 64 + dd] = fa3;
  red[(4 * 8 + w4) * 64 + dd] = fa4; red[(5 * 8 + w4) * 64 + dd] = fa5;
  red[(6 * 8 + w4) * 64 + dd] = fa6; red[(7 * 8 + w4) * 64 + dd] = fa7;
  __syncthreads();
  int l = tid >> 6, d2 = tid & 63;
  float4 s = {0,0,0,0};
#pragma unroll
  for (int ww = 0; ww < 8; ww++) {
    float4 t = red[(l * 8 + ww) * 64 + d2];
    s.x += t.x; s.y += t.y; s.z += t.z; s.w += t.w;
  }
  *(float4*)&sums9[(((size_t)(b * NT9 + g9) * NLBL + l) * DIM) + dh * 256 + d2 * 4] = s;
}

// -------- K2: E-pass + ticket-fused per-image loss tail + global aggregation --------
__global__ __launch_bounds__(256) void k_epass4(const uint4* __restrict__ bfemb4,
                                                const float* __restrict__ sums9,
                                                const int* __restrict__ labels,
                                                const float* __restrict__ cnt9,
                                                const float* __restrict__ is_forged,
                                                unsigned* __restrict__ counters,
                                                float* __restrict__ E9,
                                                float* __restrict__ per_img,
                                                float* __restrict__ out) {
  int n = blockIdx.x;                          // 45*16 = 720
  int img = ((n & 7) << 1) | ((n >> 3) & 1);   // 2 images per XCD
  int t = n >> 4;                              // 0..44 upper-tri tile
  int it = 0, rem = t;
  while (rem >= NT9 - it) { rem -= NT9 - it; it++; }
  int jt = it + rem;
  int i0 = it * 128, j0 = jt * 128;
  bool diag = (it == jt);
  int tid = threadIdx.x, lane = tid & 63, w = tid >> 6;
  int wm = w >> 1, wn = w & 1;
  int quad = lane >> 4, l15 = lane & 15;
  __shared__ float Ered[2][128];
  __shared__ float Ecol[2][128];
  __shared__ int slab[NPIX];          // tail: 4.4 KB
  __shared__ float ssum[NLBL * DIM];  // tail: 16 KB
  __shared__ float sCnt[NLBL], sR[NLBL][NLBL];
  __shared__ float sLog, sNA;
  __shared__ int isTail;

  size_t uA[4], uB[4];
#pragma unroll
  for (int f = 0; f < 4; f++) {
    uA[f] = ((size_t)(img * NGRP + it * 8 + wm * 4 + f) * 16) * 64 + lane;
    uB[f] = ((size_t)(img * NGRP + jt * 8 + wn * 4 + f) * 16) * 64 + lane;
  }

  v4f acc[4][4];
#pragma unroll
  for (int mf = 0; mf < 4; mf++)
#pragma unroll
    for (int nf = 0; nf < 4; nf++) acc[mf][nf] = (v4f){0.f, 0.f, 0.f, 0.f};

  v8s a0[4], b0[4], a1[4], b1[4];
#define LOADG(kc, AR, BR)                                               \
  {                                                                     \
    _Pragma("unroll") for (int f = 0; f < 4; f++)                       \
        AR[f] = *(const v8s*)(bfemb4 + uA[f] + (kc) * 64);              \
    _Pragma("unroll") for (int f = 0; f < 4; f++)                       \
        BR[f] = *(const v8s*)(bfemb4 + uB[f] + (kc) * 64);              \
  }
#define MFMAG(AR, BR)                                                   \
  {                                                                     \
    _Pragma("unroll") for (int mf = 0; mf < 4; mf++)                    \
        _Pragma("unroll") for (int nf = 0; nf < 4; nf++)                \
            acc[mf][nf] = __builtin_amdgcn_mfma_f32_16x16x32_bf16(      \
                AR[mf], BR[nf], acc[mf][nf], 0, 0, 0);                  \
  }

  LOADG(0, a0, b0);
#pragma unroll
  for (int kc = 0; kc < 16; kc += 2) {
    if (kc + 1 < 16) LOADG(kc + 1, a1, b1);
    MFMAG(a0, b0);
    if (kc + 2 < 16) LOADG(kc + 2, a0, b0);
    MFMAG(a1, b1);
  }
#undef LOADG
#undef MFMAG

  // epilogue: C/D layout col = lane&15, row = quad*4 + reg; rn2 == 1.
  float scol[4] = {0.f, 0.f, 0.f, 0.f};
#pragma unroll
  for (int mf = 0; mf < 4; mf++) {
#pragma unroll
    for (int rr = 0; rr < 4; rr++) {
      int i = i0 + wm * 64 + mf * 16 + quad * 4 + rr;
      float srow = 0.f;
#pragma unroll
      for (int nf = 0; nf < 4; nf++) {
        int j = j0 + wn * 64 + nf * 16 + l15;
        float e = __expf((acc[mf][nf][rr] - 1.f) * INVT);
        bool ok = (j < NPIX) && (!diag || (i != j && i < NPIX));
        e = ok ? e : 0.f;
        srow += e;
        scol[nf] += e;
      }
      srow += __shfl_xor(srow, 1); srow += __shfl_xor(srow, 2);
      srow += __shfl_xor(srow, 4); srow += __shfl_xor(srow, 8);
      if (l15 == 0) Ered[wn][wm * 64 + mf * 16 + quad * 4 + rr] = srow;
    }
  }
  if (!diag) {
#pragma unroll
    for (int nf = 0; nf < 4; nf++) {
      float s = scol[nf];
      s += __shfl_xor(s, 16); s += __shfl_xor(s, 32);
      if (quad == 0) Ecol[wm][wn * 64 + nf * 16 + l15] = s;
    }
  }
  __syncthreads();
  if (tid < 128) {
    E9[((size_t)img * NT9 + jt) * NROWPAD + i0 + tid] = Ered[0][tid] + Ered[1][tid];
    if (!diag)
      E9[((size_t)img * NT9 + it) * NROWPAD + j0 + tid] = Ecol[0][tid] + Ecol[1][tid];
  }
  // ---- per-image ticket (release) ----
  __threadfence();
  __syncthreads();
  if (tid == 0) isTail = (atomicAdd(&counters[img], 1u) == 44u);
  __syncthreads();
  if (!isTail) return;
  __threadfence();  // acquire: other blocks' E9 now visible

  // ================= per-image loss tail (45th block of this image) =================
  if (tid < NLBL) {
    float s = 0.f;
#pragma unroll
    for (int g = 0; g < NT9; g++) s += cnt9[((size_t)img * NT9 + g) * NLBL + tid];
    sCnt[tid] = s;
  }
  if (tid == 0) { sLog = 0.f; sNA = 0.f; }
  for (int p = tid; p < NPIX; p += 256) slab[p] = labels[img * NROWPAD + p];
  for (int o = tid; o < NLBL * DIM; o += 256) {
    float s = 0.f;
#pragma unroll
    for (int g = 0; g < NT9; g++) s += sums9[((size_t)(img * NT9 + g) * NLBL * DIM) + o];
    ssum[o] = s;
  }
  __syncthreads();
  float ll = 0.f, na = 0.f;
  for (int p = tid; p < NPIX; p += 256) {
    int lab = slab[p];
    if (sCnt[lab] >= 1.5f) {
      float e = 0.f;
#pragma unroll
      for (int s = 0; s < NT9; s++) e += E9[((size_t)img * NT9 + s) * NROWPAD + p];
      ll += __logf(e + 1e-6f);
      na += 1.f;
    }
  }
  ll = wave_reduce(ll); na = wave_reduce(na);
  if (lane == 0) { atomicAdd(&sLog, ll); atomicAdd(&sNA, na); }
  for (int tt0 = w; tt0 < 36; tt0 += 4) {
    int a = 0, tt = tt0;
    while (tt >= NLBL - a) { tt -= NLBL - a; a++; }
    int bb = a + tt;
    float d0 = 0.f;
    for (int k = lane; k < DIM; k += 64) d0 += ssum[a * DIM + k] * ssum[bb * DIM + k];
    d0 = wave_reduce(d0);
    if (lane == 0) sR[a][bb] = d0;
  }
  __syncthreads();
  if (tid == 0) {
    float spos = 0.f;
    for (int l = 0; l < NLBL; l++) {
      float c = sCnt[l];
      if (c >= 1.5f) spos += (sR[l][l] - c) * INVT / (c - 1.f) - c * INVT;
    }
    float nA = sNA;
    float sc = nA > 0.f ? (sLog - spos) / nA : 0.f;
    float scv = nA > 0.f ? 1.f : 0.f;
    float inv[NLBL]; int present[NLBL]; int nPres = 0;
    for (int l = 0; l < NLBL; l++) {
      present[l] = sCnt[l] > 0.f;
      nPres += present[l];
      inv[l] = 1.f / fmaxf(sCnt[l], 1.f);
    }
    float sepsum = 0.f; int npairs = 0;
    for (int a = 0; a < NLBL; a++)
      for (int c = a + 1; c < NLBL; c++)
        if (present[a] && present[c]) {
          float sq_ = sR[a][a] * inv[a] * inv[a] + sR[c][c] * inv[c] * inv[c]
                    - 2.f * sR[a][c] * inv[a] * inv[c];
          float dd = sqrtf(fmaxf(sq_, 0.f));
          sepsum += fmaxf(2.f - dd, 0.f);
          npairs++;
        }
    float sep = npairs > 0 ? sepsum / (float)npairs : 0.f;
    float sepv = nPres >= 2 ? 1.f : 0.f;
    float inst = 0.f; int nlbl = 0;
    for (int l = 0; l < NLBL; l++) {
      float var = 1.f - sR[l][l] * inv[l] * inv[l];  // q_l/c = 1
      if (sCnt[l] >= 2.f && var > 0.1f) { inst += var - 0.1f; nlbl++; }
    }
    float unif = nlbl > 0 ? inst / (float)nlbl : 0.f;
    float unifv = nlbl > 0 ? 1.f : 0.f;
    float tot2 = 0.f;
    for (int a = 0; a < NLBL; a++) {
      tot2 += sR[a][a];
      for (int c = a + 1; c < NLBL; c++) tot2 += 2.f * sR[a][c];
    }
    float Nf = (float)NPIX;
    float var_all = 1.f - tot2 / (Nf * Nf);  // totq/N = 1
    float uniu = var_all > 0.1f ? var_all - 0.1f : 0.f;
    float uniuv = var_all > 0.1f ? 1.f : 0.f;
    bool isf = is_forged[img] >= 0.5f;
    per_img[img * 6 + 0] = sc;
    per_img[img * 6 + 1] = scv;
    per_img[img * 6 + 2] = sep;
    per_img[img * 6 + 3] = sepv;
    per_img[img * 6 + 4] = isf ? unif : uniu;
    per_img[img * 6 + 5] = isf ? unifv : uniuv;
    __threadfence();  // release per_img before the global ticket
    unsigned tk = atomicAdd(&counters[16], 1u);
    if (tk == NIMG - 1) {  // last image's tail aggregates
      __threadfence();
      float accv[3] = {0.f, 0.f, 0.f}, accn[3] = {0.f, 0.f, 0.f};
      for (int bb = 0; bb < NIMG; bb++)
        for (int m = 0; m < 3; m++) {
          float v = per_img[bb * 6 + m * 2], val = per_img[bb * 6 + m * 2 + 1];
          accv[m] += v * val; accn[m] += val;
        }
      float scA = accn[0] > 0.f ? accv[0] / accn[0] : 0.f;
      float sepA = accn[1] > 0.f ? accv[1] / accn[1] : 0.f;
      float uniA = accn[2] > 0.f ? accv[2] / accn[2] : 0.f;
      out[0] = 1.0f * scA + 0.5f * sepA + 0.5f * uniA;
    }
  }
}

extern "C" void kernel_launch(void* const* d_in, const int* in_sizes, int n_in,
                              void* d_out, int out_size, void* d_ws, size_t ws_size,
                              hipStream_t stream) {
  const float* emb = (const float*)d_in[0];
  const float* masks = (const float*)d_in[1];
  const float* isf = (const float*)d_in[2];
  float* out = (float*)d_out;
  char* ws = (char*)d_ws;
  size_t off = 0;
  uint4* bfemb4 = (uint4*)(ws + off);
  off += (size_t)NIMG * NGRP * 16 * 64 * 16;                      // 18.9 MB fragment-ordered bf16
  float* E9 = (float*)(ws + off);     off += sizeof(float) * NIMG * NT9 * NROWPAD;    // 663 KB
  float* sums9 = (float*)(ws + off);  off += sizeof(float) * NIMG * NT9 * NLBL * DIM; // 2.36 MB
  int* labels = (int*)(ws + off);     off += sizeof(int) * NIMG * NROWPAD;
  float* cnt9 = (float*)(ws + off);   off += sizeof(float) * NIMG * NT9 * NLBL;
  float* per_img = (float*)(ws + off); off += sizeof(float) * NIMG * 6;
  off = (off + 127) & ~(size_t)127;
  unsigned* counters = (unsigned*)(ws + off); off += 128;  // [0..15] per-image, [16] global

  // 2 launches; no memset (owner-writes only; tickets zeroed by k_packsum)
  k_packsum<<<dim3(18, NIMG), 512, 0, stream>>>(emb, masks, (uint2*)bfemb4, sums9,
                                                labels, cnt9, counters);
  k_epass4<<<45 * NIMG, 256, 0, stream>>>(bfemb4, sums9, labels, cnt9, isf,
                                          counters, E9, per_img, out);
}

// Round 10
// 136.448 us; speedup vs baseline: 1.2810x; 1.2810x over previous
//
#include <hip/hip_runtime.h>
#include <math.h>

#define NPIX 1089
#define DIM 512
#define NIMG 16
#define NLBL 8      // labels 0..6 used, 7 = padding bucket
#define NMASK 6
#define INVT 14.2857142857142857f  // 1/0.07

#define NGRP 72     // 16-row groups per image (72*16 = 1152 padded rows)
#define NROWPAD 1152
#define NT9 9       // 128-row tiles per dim

// Embeddings are unit-normalized by the module, so rn2 == 1 (+-2e-7):
// max-subtract constant, q_l (= cnt_l), totq (= NPIX) collapse.
//
// bfemb fragment-ordered layout (uint4 units):
//   index = ((img*NGRP + g)*16 + kc)*64 + (q*16 + m),  row = g*16+m, hw = kc*32 + q*8
// => any MFMA A/B fragment load is ONE contiguous 1KB wave load.
//
// E9[img][s][1152]: 9 owner-slots per image; each (rowgroup,slot) written by
// exactly ONE epass block (plain stores, no memset, no atomics).
//
// Lesson R9: do NOT fuse the loss tail into the epass kernel -- the tail's
// LDS/VGPR needs tax every hot block (89us vs <45us). Keep kernels lean.

typedef short v8s __attribute__((ext_vector_type(8)));
typedef float v4f __attribute__((ext_vector_type(4)));

__device__ __forceinline__ float wave_reduce(float x) {
#pragma unroll
  for (int o = 32; o > 0; o >>= 1) x += __shfl_xor(x, o, 64);
  return x;
}
__device__ __forceinline__ unsigned bfbits(float x) {  // fp32 -> bf16 bits, RNE
  unsigned u = __float_as_uint(x);
  return (u + 0x7FFFu + ((u >> 16) & 1u)) >> 16;
}
__device__ __forceinline__ unsigned pk(float lo, float hi) {
  return bfbits(lo) | (bfbits(hi) << 16);
}

// -------- K1: labels + per-label counts; zeroes the final-agg ticket --------
__global__ void k_labels(const float* __restrict__ masks, int* __restrict__ labels,
                         float* __restrict__ cnt, unsigned* __restrict__ counter) {
  int b = blockIdx.x, tid = threadIdx.x;
  int lane = tid & 63, w = tid >> 6;
  __shared__ float msum[NMASK];
  __shared__ float red[4][NLBL];
  if (tid < NMASK) msum[tid] = 0.f;
  if (b == 0 && tid == 0) *counter = 0u;
  __syncthreads();
  float acc[NMASK] = {0.f, 0.f, 0.f, 0.f, 0.f, 0.f};
  for (int p = tid; p < NPIX; p += 256) {
#pragma unroll
    for (int c = 0; c < NMASK; c++) acc[c] += masks[((size_t)b * NMASK + c) * NPIX + p];
  }
#pragma unroll
  for (int c = 0; c < NMASK; c++) {
    float v = wave_reduce(acc[c]);
    if (lane == 0) atomicAdd(&msum[c], v);
  }
  __syncthreads();
  float c8[NLBL] = {0.f, 0.f, 0.f, 0.f, 0.f, 0.f, 0.f, 0.f};
  for (int p = tid; p < NPIX; p += 256) {
    int lab = 0;
#pragma unroll
    for (int c = 0; c < NMASK; c++) {
      float mv = masks[((size_t)b * NMASK + c) * NPIX + p];
      if (mv > 0.5f && msum[c] > 0.f) lab = c + 1;  // ascending overwrite == max over hits
    }
    labels[b * NPIX + p] = lab;
#pragma unroll
    for (int l = 0; l < NLBL; l++) c8[l] += (lab == l) ? 1.f : 0.f;
  }
#pragma unroll
  for (int l = 0; l < NLBL; l++) c8[l] = wave_reduce(c8[l]);
  if (lane == 0) {
#pragma unroll
    for (int l = 0; l < NLBL; l++) red[w][l] = c8[l];
  }
  __syncthreads();
  if (tid < NLBL)
    cnt[b * NLBL + tid] = red[0][tid] + red[1][tid] + red[2][tid] + red[3][tid];
}

// -------- K2: pack (fp32 -> fragment-ordered bf16) + per-label partial sums ----
// Grid (18, NIMG): blockIdx.x = g9*2 + dh. Block 512 = 8 row-streams x 64 dim-lanes.
// Row is wave-uniform -> label is wave-uniform -> uniform switch accumulate.
// Writes per-rowgroup partials sums9[img][g9][l][d] -- plain stores, no atomics.
__global__ __launch_bounds__(512) void k_packsum(const float* __restrict__ emb,
                                                 const int* __restrict__ labels,
                                                 uint2* __restrict__ bfemb2,
                                                 float* __restrict__ sums9) {
  int b = blockIdx.y;
  int g9 = blockIdx.x >> 1, dh = blockIdx.x & 1;  // 128-row group, 256-dim half
  int tid = threadIdx.x, dd = tid & 63, w4 = tid >> 6;
  __shared__ int slab[128];
  __shared__ float4 red[8 * 8 * 64];  // [l][w4][dd], 64 KB
  if (tid < 128) {
    int r = g9 * 128 + tid;
    slab[tid] = (r < NPIX) ? labels[b * NPIX + r] : 7;
  }
  __syncthreads();
  float4 fa0 = {0,0,0,0}, fa1 = {0,0,0,0}, fa2 = {0,0,0,0}, fa3 = {0,0,0,0};
  float4 fa4 = {0,0,0,0}, fa5 = {0,0,0,0}, fa6 = {0,0,0,0}, fa7 = {0,0,0,0};
  int kc = dh * 8 + (dd >> 3), q = (dd >> 1) & 3, half = dd & 1;
#pragma unroll
  for (int k = 0; k < 16; k++) {
    int r = g9 * 128 + w4 + k * 8;           // wave-uniform row
    bool v = r < NPIX;
    int rc = v ? r : (NPIX - 1);
    float4 x = ((const float4*)(emb + (size_t)(b * NPIX + rc) * DIM))[dh * 64 + dd];
    if (!v) x = make_float4(0.f, 0.f, 0.f, 0.f);
    uint2 o = make_uint2(pk(x.x, x.y), pk(x.z, x.w));
    bfemb2[((((size_t)(b * NGRP + (r >> 4)) * 16 + kc) * 64) + q * 16 + (r & 15)) * 2 + half] = o;
    int lab = __builtin_amdgcn_readfirstlane(slab[r - g9 * 128]);
    switch (lab) {
      case 0: fa0.x += x.x; fa0.y += x.y; fa0.z += x.z; fa0.w += x.w; break;
      case 1: fa1.x += x.x; fa1.y += x.y; fa1.z += x.z; fa1.w += x.w; break;
      case 2: fa2.x += x.x; fa2.y += x.y; fa2.z += x.z; fa2.w += x.w; break;
      case 3: fa3.x += x.x; fa3.y += x.y; fa3.z += x.z; fa3.w += x.w; break;
      case 4: fa4.x += x.x; fa4.y += x.y; fa4.z += x.z; fa4.w += x.w; break;
      case 5: fa5.x += x.x; fa5.y += x.y; fa5.z += x.z; fa5.w += x.w; break;
      case 6: fa6.x += x.x; fa6.y += x.y; fa6.z += x.z; fa6.w += x.w; break;
      default: fa7.x += x.x; fa7.y += x.y; fa7.z += x.z; fa7.w += x.w; break;
    }
  }
  red[(0 * 8 + w4) * 64 + dd] = fa0; red[(1 * 8 + w4) * 64 + dd] = fa1;
  red[(2 * 8 + w4) * 64 + dd] = fa2; red[(3 * 8 + w4) * 64 + dd] = fa3;
  red[(4 * 8 + w4) * 64 + dd] = fa4; red[(5 * 8 + w4) * 64 + dd] = fa5;
  red[(6 * 8 + w4) * 64 + dd] = fa6; red[(7 * 8 + w4) * 64 + dd] = fa7;
  __syncthreads();
  int l = tid >> 6, d2 = tid & 63;
  float4 s = {0,0,0,0};
#pragma unroll
  for (int ww = 0; ww < 8; ww++) {
    float4 t = red[(l * 8 + ww) * 64 + d2];
    s.x += t.x; s.y += t.y; s.z += t.z; s.w += t.w;
  }
  *(float4*)&sums9[(((size_t)(b * NT9 + g9) * NLBL + l) * DIM) + dh * 256 + d2 * 4] = s;
}

// -------- K3: E-pass, symmetric tiles (it<=jt), contiguous fragment loads,
//              LDS-merged owner-slot epilogue (E9, plain stores), lean resources ----
__global__ __launch_bounds__(256) void k_epass3(const uint4* __restrict__ bfemb4,
                                                float* __restrict__ E9) {
  int n = blockIdx.x;                          // 45*16 = 720
  int img = ((n & 7) << 1) | ((n >> 3) & 1);   // 2 images per XCD
  int t = n >> 4;                              // 0..44 upper-tri tile
  int it = 0, rem = t;
  while (rem >= NT9 - it) { rem -= NT9 - it; it++; }
  int jt = it + rem;
  int i0 = it * 128, j0 = jt * 128;
  bool diag = (it == jt);
  int tid = threadIdx.x, lane = tid & 63, w = tid >> 6;
  int wm = w >> 1, wn = w & 1;
  int quad = lane >> 4, l15 = lane & 15;
  __shared__ float Ered[2][128];
  __shared__ float Ecol[2][128];

  size_t uA[4], uB[4];
#pragma unroll
  for (int f = 0; f < 4; f++) {
    uA[f] = ((size_t)(img * NGRP + it * 8 + wm * 4 + f) * 16) * 64 + lane;
    uB[f] = ((size_t)(img * NGRP + jt * 8 + wn * 4 + f) * 16) * 64 + lane;
  }

  v4f acc[4][4];
#pragma unroll
  for (int mf = 0; mf < 4; mf++)
#pragma unroll
    for (int nf = 0; nf < 4; nf++) acc[mf][nf] = (v4f){0.f, 0.f, 0.f, 0.f};

  v8s a0[4], b0[4], a1[4], b1[4];
#define LOADG(kc, AR, BR)                                               \
  {                                                                     \
    _Pragma("unroll") for (int f = 0; f < 4; f++)                       \
        AR[f] = *(const v8s*)(bfemb4 + uA[f] + (kc) * 64);              \
    _Pragma("unroll") for (int f = 0; f < 4; f++)                       \
        BR[f] = *(const v8s*)(bfemb4 + uB[f] + (kc) * 64);              \
  }
#define MFMAG(AR, BR)                                                   \
  {                                                                     \
    _Pragma("unroll") for (int mf = 0; mf < 4; mf++)                    \
        _Pragma("unroll") for (int nf = 0; nf < 4; nf++)                \
            acc[mf][nf] = __builtin_amdgcn_mfma_f32_16x16x32_bf16(      \
                AR[mf], BR[nf], acc[mf][nf], 0, 0, 0);                  \
  }

  LOADG(0, a0, b0);
#pragma unroll
  for (int kc = 0; kc < 16; kc += 2) {
    if (kc + 1 < 16) LOADG(kc + 1, a1, b1);
    MFMAG(a0, b0);
    if (kc + 2 < 16) LOADG(kc + 2, a0, b0);
    MFMAG(a1, b1);
  }
#undef LOADG
#undef MFMAG

  // epilogue: C/D layout col = lane&15, row = quad*4 + reg; rn2 == 1.
  float scol[4] = {0.f, 0.f, 0.f, 0.f};
#pragma unroll
  for (int mf = 0; mf < 4; mf++) {
#pragma unroll
    for (int rr = 0; rr < 4; rr++) {
      int i = i0 + wm * 64 + mf * 16 + quad * 4 + rr;
      float srow = 0.f;
#pragma unroll
      for (int nf = 0; nf < 4; nf++) {
        int j = j0 + wn * 64 + nf * 16 + l15;
        float e = __expf((acc[mf][nf][rr] - 1.f) * INVT);
        bool ok = (j < NPIX) && (!diag || (i != j && i < NPIX));
        e = ok ? e : 0.f;
        srow += e;
        scol[nf] += e;
      }
      srow += __shfl_xor(srow, 1); srow += __shfl_xor(srow, 2);
      srow += __shfl_xor(srow, 4); srow += __shfl_xor(srow, 8);
      if (l15 == 0) Ered[wn][wm * 64 + mf * 16 + quad * 4 + rr] = srow;
    }
  }
  if (!diag) {
#pragma unroll
    for (int nf = 0; nf < 4; nf++) {
      float s = scol[nf];
      s += __shfl_xor(s, 16); s += __shfl_xor(s, 32);
      if (quad == 0) Ecol[wm][wn * 64 + nf * 16 + l15] = s;
    }
  }
  __syncthreads();
  if (tid < 128) {
    E9[((size_t)img * NT9 + jt) * NROWPAD + i0 + tid] = Ered[0][tid] + Ered[1][tid];
    if (!diag)
      E9[((size_t)img * NT9 + it) * NROWPAD + j0 + tid] = Ecol[0][tid] + Ecol[1][tid];
  }
}

// ---- K4: per-image losses + ticket-fused cross-image aggregation (512 threads) ----
__global__ __launch_bounds__(512) void k_imgfinal(const float* __restrict__ sums9,
                                                  const int* __restrict__ labels,
                                                  const float* __restrict__ cnt,
                                                  const float* __restrict__ E9,
                                                  const float* __restrict__ is_forged,
                                                  unsigned* __restrict__ counter,
                                                  float* __restrict__ per_img,
                                                  float* __restrict__ out) {
  int b = blockIdx.x, tid = threadIdx.x;
  int wave = tid >> 6, lane = tid & 63;
  __shared__ float ssum[NLBL * DIM];  // 16 KB reduced per-label sums
  __shared__ float sCnt[NLBL], sR[NLBL][NLBL];
  __shared__ float sLog, sNA;
  if (tid < NLBL) sCnt[tid] = cnt[b * NLBL + tid];
  if (tid == 0) { sLog = 0.f; sNA = 0.f; }
  // reduce 9 rowgroup partial sums -> ssum
  for (int o = tid; o < NLBL * DIM; o += 512) {
    float s = 0.f;
#pragma unroll
    for (int g = 0; g < NT9; g++) s += sums9[((size_t)(b * NT9 + g) * NLBL * DIM) + o];
    ssum[o] = s;
  }
  __syncthreads();
  // sum of log(E_p + 1e-6) over valid anchors (9 owner slots)
  float ll = 0.f, na = 0.f;
  for (int p = tid; p < NPIX; p += 512) {
    int lab = labels[b * NPIX + p];
    if (sCnt[lab] >= 1.5f) {
      float e = 0.f;
#pragma unroll
      for (int s = 0; s < NT9; s++) e += E9[((size_t)b * NT9 + s) * NROWPAD + p];
      ll += __logf(e + 1e-6f);
      na += 1.f;
    }
  }
  ll = wave_reduce(ll); na = wave_reduce(na);
  if (lane == 0) { atomicAdd(&sLog, ll); atomicAdd(&sNA, na); }
  // Gram of raw label sums (from LDS)
  for (int t = wave; t < 36; t += 8) {
    int a = 0, tt = t;
    while (tt >= NLBL - a) { tt -= NLBL - a; a++; }
    int bb = a + tt;
    float d0 = 0.f;
    for (int k = lane; k < DIM; k += 64) d0 += ssum[a * DIM + k] * ssum[bb * DIM + k];
    d0 = wave_reduce(d0);
    if (lane == 0) sR[a][bb] = d0;
  }
  __syncthreads();
  if (tid == 0) {
    float spos = 0.f;
    for (int l = 0; l < NLBL; l++) {
      float c = sCnt[l];
      if (c >= 1.5f) spos += (sR[l][l] - c) * INVT / (c - 1.f) - c * INVT;
    }
    float nA = sNA;
    float sc = nA > 0.f ? (sLog - spos) / nA : 0.f;
    float scv = nA > 0.f ? 1.f : 0.f;
    float inv[NLBL]; int present[NLBL]; int nPres = 0;
    for (int l = 0; l < NLBL; l++) {
      present[l] = sCnt[l] > 0.f;
      nPres += present[l];
      inv[l] = 1.f / fmaxf(sCnt[l], 1.f);
    }
    float sepsum = 0.f; int npairs = 0;
    for (int a = 0; a < NLBL; a++)
      for (int c = a + 1; c < NLBL; c++)
        if (present[a] && present[c]) {
          float sq_ = sR[a][a] * inv[a] * inv[a] + sR[c][c] * inv[c] * inv[c]
                    - 2.f * sR[a][c] * inv[a] * inv[c];
          float dd = sqrtf(fmaxf(sq_, 0.f));
          sepsum += fmaxf(2.f - dd, 0.f);
          npairs++;
        }
    float sep = npairs > 0 ? sepsum / (float)npairs : 0.f;
    float sepv = nPres >= 2 ? 1.f : 0.f;
    float inst = 0.f; int nlbl = 0;
    for (int l = 0; l < NLBL; l++) {
      float var = 1.f - sR[l][l] * inv[l] * inv[l];  // q_l/c = 1
      if (sCnt[l] >= 2.f && var > 0.1f) { inst += var - 0.1f; nlbl++; }
    }
    float unif = nlbl > 0 ? inst / (float)nlbl : 0.f;
    float unifv = nlbl > 0 ? 1.f : 0.f;
    float tot2 = 0.f;
    for (int a = 0; a < NLBL; a++) {
      tot2 += sR[a][a];
      for (int c = a + 1; c < NLBL; c++) tot2 += 2.f * sR[a][c];
    }
    float Nf = (float)NPIX;
    float var_all = 1.f - tot2 / (Nf * Nf);  // totq/N = 1
    float uniu = var_all > 0.1f ? var_all - 0.1f : 0.f;
    float uniuv = var_all > 0.1f ? 1.f : 0.f;
    bool isf = is_forged[b] >= 0.5f;
    per_img[b * 6 + 0] = sc;
    per_img[b * 6 + 1] = scv;
    per_img[b * 6 + 2] = sep;
    per_img[b * 6 + 3] = sepv;
    per_img[b * 6 + 4] = isf ? unif : uniu;
    per_img[b * 6 + 5] = isf ? unifv : uniuv;
    __threadfence();  // release per_img before the ticket
    unsigned tk = atomicAdd(counter, 1u);
    if (tk == NIMG - 1) {  // last block aggregates
      __threadfence();
      float accv[3] = {0.f, 0.f, 0.f}, accn[3] = {0.f, 0.f, 0.f};
      for (int bb = 0; bb < NIMG; bb++)
        for (int m = 0; m < 3; m++) {
          float v = per_img[bb * 6 + m * 2], val = per_img[bb * 6 + m * 2 + 1];
          accv[m] += v * val; accn[m] += val;
        }
      float scA = accn[0] > 0.f ? accv[0] / accn[0] : 0.f;
      float sepA = accn[1] > 0.f ? accv[1] / accn[1] : 0.f;
      float uniA = accn[2] > 0.f ? accv[2] / accn[2] : 0.f;
      out[0] = 1.0f * scA + 0.5f * sepA + 0.5f * uniA;
    }
  }
}

extern "C" void kernel_launch(void* const* d_in, const int* in_sizes, int n_in,
                              void* d_out, int out_size, void* d_ws, size_t ws_size,
                              hipStream_t stream) {
  const float* emb = (const float*)d_in[0];
  const float* masks = (const float*)d_in[1];
  const float* isf = (const float*)d_in[2];
  float* out = (float*)d_out;
  char* ws = (char*)d_ws;
  size_t off = 0;
  uint4* bfemb4 = (uint4*)(ws + off);
  off += (size_t)NIMG * NGRP * 16 * 64 * 16;                      // 18.9 MB fragment-ordered bf16
  float* E9 = (float*)(ws + off);     off += sizeof(float) * NIMG * NT9 * NROWPAD;    // 663 KB
  float* sums9 = (float*)(ws + off);  off += sizeof(float) * NIMG * NT9 * NLBL * DIM; // 2.36 MB
  int* labels = (int*)(ws + off);     off += sizeof(int) * NIMG * NPIX;
  float* cnt = (float*)(ws + off);    off += sizeof(float) * NIMG * NLBL;
  float* per_img = (float*)(ws + off); off += sizeof(float) * NIMG * 6;
  off = (off + 127) & ~(size_t)127;
  unsigned* counter = (unsigned*)(ws + off); off += 128;

  // 4 launches; no memset (owner-writes only; ticket zeroed by k_labels)
  k_labels<<<NIMG, 256, 0, stream>>>(masks, labels, cnt, counter);
  k_packsum<<<dim3(18, NIMG), 512, 0, stream>>>(emb, labels, (uint2*)bfemb4, sums9);
  k_epass3<<<45 * NIMG, 256, 0, stream>>>(bfemb4, E9);
  k_imgfinal<<<NIMG, 512, 0, stream>>>(sums9, labels, cnt, E9, isf, counter, per_img, out);
}

// Round 11
// 132.309 us; speedup vs baseline: 1.3211x; 1.0313x over previous
//
#include <hip/hip_runtime.h>
#include <math.h>

#define NPIX 1089
#define DIM 512
#define NIMG 16
#define NLBL 8      // labels 0..6 used, 7 = padding bucket
#define NMASK 6
#define INVT 14.2857142857142857f  // 1/0.07

#define NGRP 72     // 16-row groups per image (72*16 = 1152 padded rows)
#define NROWPAD 1152
#define NT9 9       // 128-row tiles per dim

// Embeddings are unit-normalized by the module, so rn2 == 1 (+-2e-7):
// max-subtract constant, q_l (= cnt_l), totq (= NPIX) collapse.
//
// bfemb fragment-ordered layout (uint4 units):
//   index = ((img*NGRP + g)*16 + kc)*64 + (q*16 + m),  row = g*16+m, hw = kc*32 + q*8
// => any MFMA A/B fragment load is ONE contiguous 1KB wave load.
//
// E9[img][s][1152]: 9 owner-slots per image; each (rowgroup,slot) written by
// exactly ONE epass block (plain stores, no memset, no atomics).
//
// Lesson R9: do NOT fuse the loss tail into the epass kernel (cold-path LDS/VGPR
// taxes every hot block: 89us vs <45us). Lesson R10: k_labels as a standalone
// 16-block kernel costs ~8us + a drain gap; its work duplicates into packsum
// for ~2us (L2-hot mask re-reads).

typedef short v8s __attribute__((ext_vector_type(8)));
typedef float v4f __attribute__((ext_vector_type(4)));

__device__ __forceinline__ float wave_reduce(float x) {
#pragma unroll
  for (int o = 32; o > 0; o >>= 1) x += __shfl_xor(x, o, 64);
  return x;
}
__device__ __forceinline__ unsigned bfbits(float x) {  // fp32 -> bf16 bits, RNE
  unsigned u = __float_as_uint(x);
  return (u + 0x7FFFu + ((u >> 16) & 1u)) >> 16;
}
__device__ __forceinline__ unsigned pk(float lo, float hi) {
  return bfbits(lo) | (bfbits(hi) << 16);
}

// -------- K1: fused labels + pack (fp32 -> fragment-ordered bf16) + partial sums ----
// Grid (18, NIMG): blockIdx.x = g9*2 + dh. Block 512 = 8 row-streams x 64 dim-lanes.
// Each block derives its own 128-row label slab from masks (~2us total dup work);
// dh==0 blocks export labels[] and per-group counts cnt9[]. Row is wave-uniform
// -> label is wave-uniform -> uniform switch accumulate (1 add/element).
// Block (0,0) zeroes the imgfinal aggregation ticket.
__global__ __launch_bounds__(512) void k_packsum(const float* __restrict__ emb,
                                                 const float* __restrict__ masks,
                                                 uint2* __restrict__ bfemb2,
                                                 float* __restrict__ sums9,
                                                 int* __restrict__ labels,
                                                 float* __restrict__ cnt9,
                                                 unsigned* __restrict__ counter) {
  int b = blockIdx.y;
  int g9 = blockIdx.x >> 1, dh = blockIdx.x & 1;  // 128-row group, 256-dim half
  int tid = threadIdx.x, dd = tid & 63, w4 = tid >> 6, lane = tid & 63;
  __shared__ float msum[NMASK];
  __shared__ int slab[128];
  __shared__ int scnt[NLBL];
  __shared__ float4 red[8 * 8 * 64];  // [l][w4][dd], 64 KB
  if (tid < NMASK) msum[tid] = 0.f;
  if (tid < NLBL) scnt[tid] = 0;
  if (b == 0 && blockIdx.x == 0 && tid == 0) *counter = 0u;
  __syncthreads();
  // per-channel mask sums (active test) -- L2-hot, 3 iters
  {
    float am[NMASK] = {0.f, 0.f, 0.f, 0.f, 0.f, 0.f};
    for (int p = tid; p < NPIX; p += 512) {
#pragma unroll
      for (int c = 0; c < NMASK; c++) am[c] += masks[((size_t)b * NMASK + c) * NPIX + p];
    }
#pragma unroll
    for (int c = 0; c < NMASK; c++) {
      float v = wave_reduce(am[c]);
      if (lane == 0) atomicAdd(&msum[c], v);
    }
  }
  __syncthreads();
  if (tid < 128) {
    int r = g9 * 128 + tid;
    int lab = 7;
    if (r < NPIX) {
      lab = 0;
#pragma unroll
      for (int c = 0; c < NMASK; c++) {
        float mv = masks[((size_t)b * NMASK + c) * NPIX + r];
        if (mv > 0.5f && msum[c] > 0.f) lab = c + 1;  // ascending overwrite == max over hits
      }
    }
    slab[tid] = lab;
    if (dh == 0) {
      labels[b * NROWPAD + r] = lab;
      if (r < NPIX) atomicAdd(&scnt[lab], 1);   // exclude pad rows
    }
  }
  __syncthreads();
  if (dh == 0 && tid < NLBL) cnt9[((size_t)b * NT9 + g9) * NLBL + tid] = (float)scnt[tid];
  float4 fa0 = {0,0,0,0}, fa1 = {0,0,0,0}, fa2 = {0,0,0,0}, fa3 = {0,0,0,0};
  float4 fa4 = {0,0,0,0}, fa5 = {0,0,0,0}, fa6 = {0,0,0,0}, fa7 = {0,0,0,0};
  int kc = dh * 8 + (dd >> 3), q = (dd >> 1) & 3, half = dd & 1;
#pragma unroll
  for (int k = 0; k < 16; k++) {
    int r = g9 * 128 + w4 + k * 8;           // wave-uniform row
    bool v = r < NPIX;
    int rc = v ? r : (NPIX - 1);
    float4 x = ((const float4*)(emb + (size_t)(b * NPIX + rc) * DIM))[dh * 64 + dd];
    if (!v) x = make_float4(0.f, 0.f, 0.f, 0.f);
    uint2 o = make_uint2(pk(x.x, x.y), pk(x.z, x.w));
    bfemb2[((((size_t)(b * NGRP + (r >> 4)) * 16 + kc) * 64) + q * 16 + (r & 15)) * 2 + half] = o;
    int lab = __builtin_amdgcn_readfirstlane(slab[r - g9 * 128]);
    switch (lab) {
      case 0: fa0.x += x.x; fa0.y += x.y; fa0.z += x.z; fa0.w += x.w; break;
      case 1: fa1.x += x.x; fa1.y += x.y; fa1.z += x.z; fa1.w += x.w; break;
      case 2: fa2.x += x.x; fa2.y += x.y; fa2.z += x.z; fa2.w += x.w; break;
      case 3: fa3.x += x.x; fa3.y += x.y; fa3.z += x.z; fa3.w += x.w; break;
      case 4: fa4.x += x.x; fa4.y += x.y; fa4.z += x.z; fa4.w += x.w; break;
      case 5: fa5.x += x.x; fa5.y += x.y; fa5.z += x.z; fa5.w += x.w; break;
      case 6: fa6.x += x.x; fa6.y += x.y; fa6.z += x.z; fa6.w += x.w; break;
      default: fa7.x += x.x; fa7.y += x.y; fa7.z += x.z; fa7.w += x.w; break;
    }
  }
  red[(0 * 8 + w4) * 64 + dd] = fa0; red[(1 * 8 + w4) * 64 + dd] = fa1;
  red[(2 * 8 + w4) * 64 + dd] = fa2; red[(3 * 8 + w4) * 64 + dd] = fa3;
  red[(4 * 8 + w4) * 64 + dd] = fa4; red[(5 * 8 + w4) * 64 + dd] = fa5;
  red[(6 * 8 + w4) * 64 + dd] = fa6; red[(7 * 8 + w4) * 64 + dd] = fa7;
  __syncthreads();
  int l = tid >> 6, d2 = tid & 63;
  float4 s = {0,0,0,0};
#pragma unroll
  for (int ww = 0; ww < 8; ww++) {
    float4 t = red[(l * 8 + ww) * 64 + d2];
    s.x += t.x; s.y += t.y; s.z += t.z; s.w += t.w;
  }
  *(float4*)&sums9[(((size_t)(b * NT9 + g9) * NLBL + l) * DIM) + dh * 256 + d2 * 4] = s;
}

// -------- K2: E-pass, symmetric tiles (it<=jt), contiguous fragment loads,
//              LDS-merged owner-slot epilogue (E9, plain stores), lean resources ----
__global__ __launch_bounds__(256) void k_epass3(const uint4* __restrict__ bfemb4,
                                                float* __restrict__ E9) {
  int n = blockIdx.x;                          // 45*16 = 720
  int img = ((n & 7) << 1) | ((n >> 3) & 1);   // 2 images per XCD
  int t = n >> 4;                              // 0..44 upper-tri tile
  int it = 0, rem = t;
  while (rem >= NT9 - it) { rem -= NT9 - it; it++; }
  int jt = it + rem;
  int i0 = it * 128, j0 = jt * 128;
  bool diag = (it == jt);
  int tid = threadIdx.x, lane = tid & 63, w = tid >> 6;
  int wm = w >> 1, wn = w & 1;
  int quad = lane >> 4, l15 = lane & 15;
  __shared__ float Ered[2][128];
  __shared__ float Ecol[2][128];

  size_t uA[4], uB[4];
#pragma unroll
  for (int f = 0; f < 4; f++) {
    uA[f] = ((size_t)(img * NGRP + it * 8 + wm * 4 + f) * 16) * 64 + lane;
    uB[f] = ((size_t)(img * NGRP + jt * 8 + wn * 4 + f) * 16) * 64 + lane;
  }

  v4f acc[4][4];
#pragma unroll
  for (int mf = 0; mf < 4; mf++)
#pragma unroll
    for (int nf = 0; nf < 4; nf++) acc[mf][nf] = (v4f){0.f, 0.f, 0.f, 0.f};

  v8s a0[4], b0[4], a1[4], b1[4];
#define LOADG(kc, AR, BR)                                               \
  {                                                                     \
    _Pragma("unroll") for (int f = 0; f < 4; f++)                       \
        AR[f] = *(const v8s*)(bfemb4 + uA[f] + (kc) * 64);              \
    _Pragma("unroll") for (int f = 0; f < 4; f++)                       \
        BR[f] = *(const v8s*)(bfemb4 + uB[f] + (kc) * 64);              \
  }
#define MFMAG(AR, BR)                                                   \
  {                                                                     \
    _Pragma("unroll") for (int mf = 0; mf < 4; mf++)                    \
        _Pragma("unroll") for (int nf = 0; nf < 4; nf++)                \
            acc[mf][nf] = __builtin_amdgcn_mfma_f32_16x16x32_bf16(      \
                AR[mf], BR[nf], acc[mf][nf], 0, 0, 0);                  \
  }

  LOADG(0, a0, b0);
#pragma unroll
  for (int kc = 0; kc < 16; kc += 2) {
    if (kc + 1 < 16) LOADG(kc + 1, a1, b1);
    MFMAG(a0, b0);
    if (kc + 2 < 16) LOADG(kc + 2, a0, b0);
    MFMAG(a1, b1);
  }
#undef LOADG
#undef MFMAG

  // epilogue: C/D layout col = lane&15, row = quad*4 + reg; rn2 == 1.
  float scol[4] = {0.f, 0.f, 0.f, 0.f};
#pragma unroll
  for (int mf = 0; mf < 4; mf++) {
#pragma unroll
    for (int rr = 0; rr < 4; rr++) {
      int i = i0 + wm * 64 + mf * 16 + quad * 4 + rr;
      float srow = 0.f;
#pragma unroll
      for (int nf = 0; nf < 4; nf++) {
        int j = j0 + wn * 64 + nf * 16 + l15;
        float e = __expf((acc[mf][nf][rr] - 1.f) * INVT);
        bool ok = (j < NPIX) && (!diag || (i != j && i < NPIX));
        e = ok ? e : 0.f;
        srow += e;
        scol[nf] += e;
      }
      srow += __shfl_xor(srow, 1); srow += __shfl_xor(srow, 2);
      srow += __shfl_xor(srow, 4); srow += __shfl_xor(srow, 8);
      if (l15 == 0) Ered[wn][wm * 64 + mf * 16 + quad * 4 + rr] = srow;
    }
  }
  if (!diag) {
#pragma unroll
    for (int nf = 0; nf < 4; nf++) {
      float s = scol[nf];
      s += __shfl_xor(s, 16); s += __shfl_xor(s, 32);
      if (quad == 0) Ecol[wm][wn * 64 + nf * 16 + l15] = s;
    }
  }
  __syncthreads();
  if (tid < 128) {
    E9[((size_t)img * NT9 + jt) * NROWPAD + i0 + tid] = Ered[0][tid] + Ered[1][tid];
    if (!diag)
      E9[((size_t)img * NT9 + it) * NROWPAD + j0 + tid] = Ecol[0][tid] + Ecol[1][tid];
  }
}

// ---- K3: per-image losses + ticket-fused cross-image aggregation (512 threads) ----
__global__ __launch_bounds__(512) void k_imgfinal(const float* __restrict__ sums9,
                                                  const int* __restrict__ labels,
                                                  const float* __restrict__ cnt9,
                                                  const float* __restrict__ E9,
                                                  const float* __restrict__ is_forged,
                                                  unsigned* __restrict__ counter,
                                                  float* __restrict__ per_img,
                                                  float* __restrict__ out) {
  int b = blockIdx.x, tid = threadIdx.x;
  int wave = tid >> 6, lane = tid & 63;
  __shared__ float ssum[NLBL * DIM];  // 16 KB reduced per-label sums
  __shared__ float sCnt[NLBL], sR[NLBL][NLBL];
  __shared__ float sLog, sNA;
  if (tid < NLBL) {
    float s = 0.f;
#pragma unroll
    for (int g = 0; g < NT9; g++) s += cnt9[((size_t)b * NT9 + g) * NLBL + tid];
    sCnt[tid] = s;
  }
  if (tid == 0) { sLog = 0.f; sNA = 0.f; }
  // reduce 9 rowgroup partial sums -> ssum
  for (int o = tid; o < NLBL * DIM; o += 512) {
    float s = 0.f;
#pragma unroll
    for (int g = 0; g < NT9; g++) s += sums9[((size_t)(b * NT9 + g) * NLBL * DIM) + o];
    ssum[o] = s;
  }
  __syncthreads();
  // sum of log(E_p + 1e-6) over valid anchors (9 owner slots)
  float ll = 0.f, na = 0.f;
  for (int p = tid; p < NPIX; p += 512) {
    int lab = labels[b * NROWPAD + p];
    if (sCnt[lab] >= 1.5f) {
      float e = 0.f;
#pragma unroll
      for (int s = 0; s < NT9; s++) e += E9[((size_t)b * NT9 + s) * NROWPAD + p];
      ll += __logf(e + 1e-6f);
      na += 1.f;
    }
  }
  ll = wave_reduce(ll); na = wave_reduce(na);
  if (lane == 0) { atomicAdd(&sLog, ll); atomicAdd(&sNA, na); }
  // Gram of raw label sums (from LDS)
  for (int t = wave; t < 36; t += 8) {
    int a = 0, tt = t;
    while (tt >= NLBL - a) { tt -= NLBL - a; a++; }
    int bb = a + tt;
    float d0 = 0.f;
    for (int k = lane; k < DIM; k += 64) d0 += ssum[a * DIM + k] * ssum[bb * DIM + k];
    d0 = wave_reduce(d0);
    if (lane == 0) sR[a][bb] = d0;
  }
  __syncthreads();
  if (tid == 0) {
    float spos = 0.f;
    for (int l = 0; l < NLBL; l++) {
      float c = sCnt[l];
      if (c >= 1.5f) spos += (sR[l][l] - c) * INVT / (c - 1.f) - c * INVT;
    }
    float nA = sNA;
    float sc = nA > 0.f ? (sLog - spos) / nA : 0.f;
    float scv = nA > 0.f ? 1.f : 0.f;
    float inv[NLBL]; int present[NLBL]; int nPres = 0;
    for (int l = 0; l < NLBL; l++) {
      present[l] = sCnt[l] > 0.f;
      nPres += present[l];
      inv[l] = 1.f / fmaxf(sCnt[l], 1.f);
    }
    float sepsum = 0.f; int npairs = 0;
    for (int a = 0; a < NLBL; a++)
      for (int c = a + 1; c < NLBL; c++)
        if (present[a] && present[c]) {
          float sq_ = sR[a][a] * inv[a] * inv[a] + sR[c][c] * inv[c] * inv[c]
                    - 2.f * sR[a][c] * inv[a] * inv[c];
          float dd = sqrtf(fmaxf(sq_, 0.f));
          sepsum += fmaxf(2.f - dd, 0.f);
          npairs++;
        }
    float sep = npairs > 0 ? sepsum / (float)npairs : 0.f;
    float sepv = nPres >= 2 ? 1.f : 0.f;
    float inst = 0.f; int nlbl = 0;
    for (int l = 0; l < NLBL; l++) {
      float var = 1.f - sR[l][l] * inv[l] * inv[l];  // q_l/c = 1
      if (sCnt[l] >= 2.f && var > 0.1f) { inst += var - 0.1f; nlbl++; }
    }
    float unif = nlbl > 0 ? inst / (float)nlbl : 0.f;
    float unifv = nlbl > 0 ? 1.f : 0.f;
    float tot2 = 0.f;
    for (int a = 0; a < NLBL; a++) {
      tot2 += sR[a][a];
      for (int c = a + 1; c < NLBL; c++) tot2 += 2.f * sR[a][c];
    }
    float Nf = (float)NPIX;
    float var_all = 1.f - tot2 / (Nf * Nf);  // totq/N = 1
    float uniu = var_all > 0.1f ? var_all - 0.1f : 0.f;
    float uniuv = var_all > 0.1f ? 1.f : 0.f;
    bool isf = is_forged[b] >= 0.5f;
    per_img[b * 6 + 0] = sc;
    per_img[b * 6 + 1] = scv;
    per_img[b * 6 + 2] = sep;
    per_img[b * 6 + 3] = sepv;
    per_img[b * 6 + 4] = isf ? unif : uniu;
    per_img[b * 6 + 5] = isf ? unifv : uniuv;
    __threadfence();  // release per_img before the ticket
    unsigned tk = atomicAdd(counter, 1u);
    if (tk == NIMG - 1) {  // last block aggregates
      __threadfence();
      float accv[3] = {0.f, 0.f, 0.f}, accn[3] = {0.f, 0.f, 0.f};
      for (int bb = 0; bb < NIMG; bb++)
        for (int m = 0; m < 3; m++) {
          float v = per_img[bb * 6 + m * 2], val = per_img[bb * 6 + m * 2 + 1];
          accv[m] += v * val; accn[m] += val;
        }
      float scA = accn[0] > 0.f ? accv[0] / accn[0] : 0.f;
      float sepA = accn[1] > 0.f ? accv[1] / accn[1] : 0.f;
      float uniA = accn[2] > 0.f ? accv[2] / accn[2] : 0.f;
      out[0] = 1.0f * scA + 0.5f * sepA + 0.5f * uniA;
    }
  }
}

extern "C" void kernel_launch(void* const* d_in, const int* in_sizes, int n_in,
                              void* d_out, int out_size, void* d_ws, size_t ws_size,
                              hipStream_t stream) {
  const float* emb = (const float*)d_in[0];
  const float* masks = (const float*)d_in[1];
  const float* isf = (const float*)d_in[2];
  float* out = (float*)d_out;
  char* ws = (char*)d_ws;
  size_t off = 0;
  uint4* bfemb4 = (uint4*)(ws + off);
  off += (size_t)NIMG * NGRP * 16 * 64 * 16;                      // 18.9 MB fragment-ordered bf16
  float* E9 = (float*)(ws + off);     off += sizeof(float) * NIMG * NT9 * NROWPAD;    // 663 KB
  float* sums9 = (float*)(ws + off);  off += sizeof(float) * NIMG * NT9 * NLBL * DIM; // 2.36 MB
  int* labels = (int*)(ws + off);     off += sizeof(int) * NIMG * NROWPAD;
  float* cnt9 = (float*)(ws + off);   off += sizeof(float) * NIMG * NT9 * NLBL;
  float* per_img = (float*)(ws + off); off += sizeof(float) * NIMG * 6;
  off = (off + 127) & ~(size_t)127;
  unsigned* counter = (unsigned*)(ws + off); off += 128;

  // 3 launches; no memset (owner-writes only; ticket zeroed by k_packsum)
  k_packsum<<<dim3(18, NIMG), 512, 0, stream>>>(emb, masks, (uint2*)bfemb4, sums9,
                                                labels, cnt9, counter);
  k_epass3<<<45 * NIMG, 256, 0, stream>>>(bfemb4, E9);
  k_imgfinal<<<NIMG, 512, 0, stream>>>(sums9, labels, cnt9, E9, isf, counter, per_img, out);
}

// Round 12
// 130.842 us; speedup vs baseline: 1.3359x; 1.0112x over previous
//
#include <hip/hip_runtime.h>
#include <math.h>

#define NPIX 1089
#define DIM 512
#define NIMG 16
#define NLBL 8      // labels 0..6 used, 7 = padding bucket
#define NMASK 6
#define INVT 14.2857142857142857f  // 1/0.07

#define NGRP 72     // 16-row groups per image (72*16 = 1152 padded rows)
#define NROWPAD 1152
#define NT9 9       // 128-row tiles per dim

// Embeddings are unit-normalized by the module, so rn2 == 1 (+-2e-7):
// max-subtract constant, q_l (= cnt_l), totq (= NPIX) collapse.
//
// bfemb fragment-ordered layout (uint4 units):
//   index = ((img*NGRP + g)*16 + kc)*64 + (q*16 + m),  row = g*16+m, hw = kc*32 + q*8
// => any MFMA A/B fragment load is ONE contiguous 1KB wave load.
//
// E9[img][s][1152]: 9 owner-slots per image; each (rowgroup,slot) written by
// exactly ONE epass block (plain stores, no memset, no atomics).
//
// Lessons: R9 -- don't fuse cold tails into hot kernels (LDS/VGPR tax).
// R10/R11 -- standalone trivial kernels cost ~8us+gap; duplicate their work.
// R12 -- epass is L2-latency-bound at 11 waves/CU; widen to 8 waves/block
// (64x32 per wave) for ~22 waves/CU.

typedef short v8s __attribute__((ext_vector_type(8)));
typedef float v4f __attribute__((ext_vector_type(4)));

__device__ __forceinline__ float wave_reduce(float x) {
#pragma unroll
  for (int o = 32; o > 0; o >>= 1) x += __shfl_xor(x, o, 64);
  return x;
}
__device__ __forceinline__ unsigned bfbits(float x) {  // fp32 -> bf16 bits, RNE
  unsigned u = __float_as_uint(x);
  return (u + 0x7FFFu + ((u >> 16) & 1u)) >> 16;
}
__device__ __forceinline__ unsigned pk(float lo, float hi) {
  return bfbits(lo) | (bfbits(hi) << 16);
}

// -------- K1: fused labels + pack (fp32 -> fragment-ordered bf16) + partial sums ----
__global__ __launch_bounds__(512) void k_packsum(const float* __restrict__ emb,
                                                 const float* __restrict__ masks,
                                                 uint2* __restrict__ bfemb2,
                                                 float* __restrict__ sums9,
                                                 int* __restrict__ labels,
                                                 float* __restrict__ cnt9,
                                                 unsigned* __restrict__ counter) {
  int b = blockIdx.y;
  int g9 = blockIdx.x >> 1, dh = blockIdx.x & 1;  // 128-row group, 256-dim half
  int tid = threadIdx.x, dd = tid & 63, w4 = tid >> 6, lane = tid & 63;
  __shared__ float msum[NMASK];
  __shared__ int slab[128];
  __shared__ int scnt[NLBL];
  __shared__ float4 red[8 * 8 * 64];  // [l][w4][dd], 64 KB
  if (tid < NMASK) msum[tid] = 0.f;
  if (tid < NLBL) scnt[tid] = 0;
  if (b == 0 && blockIdx.x == 0 && tid == 0) *counter = 0u;
  __syncthreads();
  // per-channel mask sums (active test) -- L2-hot
  {
    float am[NMASK] = {0.f, 0.f, 0.f, 0.f, 0.f, 0.f};
    for (int p = tid; p < NPIX; p += 512) {
#pragma unroll
      for (int c = 0; c < NMASK; c++) am[c] += masks[((size_t)b * NMASK + c) * NPIX + p];
    }
#pragma unroll
    for (int c = 0; c < NMASK; c++) {
      float v = wave_reduce(am[c]);
      if (lane == 0) atomicAdd(&msum[c], v);
    }
  }
  __syncthreads();
  if (tid < 128) {
    int r = g9 * 128 + tid;
    int lab = 7;
    if (r < NPIX) {
      lab = 0;
#pragma unroll
      for (int c = 0; c < NMASK; c++) {
        float mv = masks[((size_t)b * NMASK + c) * NPIX + r];
        if (mv > 0.5f && msum[c] > 0.f) lab = c + 1;  // ascending overwrite == max over hits
      }
    }
    slab[tid] = lab;
    if (dh == 0) {
      labels[b * NROWPAD + r] = lab;
      if (r < NPIX) atomicAdd(&scnt[lab], 1);   // exclude pad rows
    }
  }
  __syncthreads();
  if (dh == 0 && tid < NLBL) cnt9[((size_t)b * NT9 + g9) * NLBL + tid] = (float)scnt[tid];
  float4 fa0 = {0,0,0,0}, fa1 = {0,0,0,0}, fa2 = {0,0,0,0}, fa3 = {0,0,0,0};
  float4 fa4 = {0,0,0,0}, fa5 = {0,0,0,0}, fa6 = {0,0,0,0}, fa7 = {0,0,0,0};
  int kc = dh * 8 + (dd >> 3), q = (dd >> 1) & 3, half = dd & 1;
#pragma unroll
  for (int k = 0; k < 16; k++) {
    int r = g9 * 128 + w4 + k * 8;           // wave-uniform row
    bool v = r < NPIX;
    int rc = v ? r : (NPIX - 1);
    float4 x = ((const float4*)(emb + (size_t)(b * NPIX + rc) * DIM))[dh * 64 + dd];
    if (!v) x = make_float4(0.f, 0.f, 0.f, 0.f);
    uint2 o = make_uint2(pk(x.x, x.y), pk(x.z, x.w));
    bfemb2[((((size_t)(b * NGRP + (r >> 4)) * 16 + kc) * 64) + q * 16 + (r & 15)) * 2 + half] = o;
    int lab = __builtin_amdgcn_readfirstlane(slab[r - g9 * 128]);
    switch (lab) {
      case 0: fa0.x += x.x; fa0.y += x.y; fa0.z += x.z; fa0.w += x.w; break;
      case 1: fa1.x += x.x; fa1.y += x.y; fa1.z += x.z; fa1.w += x.w; break;
      case 2: fa2.x += x.x; fa2.y += x.y; fa2.z += x.z; fa2.w += x.w; break;
      case 3: fa3.x += x.x; fa3.y += x.y; fa3.z += x.z; fa3.w += x.w; break;
      case 4: fa4.x += x.x; fa4.y += x.y; fa4.z += x.z; fa4.w += x.w; break;
      case 5: fa5.x += x.x; fa5.y += x.y; fa5.z += x.z; fa5.w += x.w; break;
      case 6: fa6.x += x.x; fa6.y += x.y; fa6.z += x.z; fa6.w += x.w; break;
      default: fa7.x += x.x; fa7.y += x.y; fa7.z += x.z; fa7.w += x.w; break;
    }
  }
  red[(0 * 8 + w4) * 64 + dd] = fa0; red[(1 * 8 + w4) * 64 + dd] = fa1;
  red[(2 * 8 + w4) * 64 + dd] = fa2; red[(3 * 8 + w4) * 64 + dd] = fa3;
  red[(4 * 8 + w4) * 64 + dd] = fa4; red[(5 * 8 + w4) * 64 + dd] = fa5;
  red[(6 * 8 + w4) * 64 + dd] = fa6; red[(7 * 8 + w4) * 64 + dd] = fa7;
  __syncthreads();
  int l = tid >> 6, d2 = tid & 63;
  float4 s = {0,0,0,0};
#pragma unroll
  for (int ww = 0; ww < 8; ww++) {
    float4 t = red[(l * 8 + ww) * 64 + d2];
    s.x += t.x; s.y += t.y; s.z += t.z; s.w += t.w;
  }
  *(float4*)&sums9[(((size_t)(b * NT9 + g9) * NLBL + l) * DIM) + dh * 256 + d2 * 4] = s;
}

// -------- K2: E-pass, symmetric tiles (it<=jt), 8 waves/block (64x32 per wave),
//              contiguous fragment loads, LDS-merged owner-slot epilogue --------
__global__ __launch_bounds__(512) void k_epass5(const uint4* __restrict__ bfemb4,
                                                float* __restrict__ E9) {
  int n = blockIdx.x;                          // 45*16 = 720
  int img = ((n & 7) << 1) | ((n >> 3) & 1);   // 2 images per XCD
  int t = n >> 4;                              // 0..44 upper-tri tile
  int it = 0, rem = t;
  while (rem >= NT9 - it) { rem -= NT9 - it; it++; }
  int jt = it + rem;
  int i0 = it * 128, j0 = jt * 128;
  bool diag = (it == jt);
  int tid = threadIdx.x, lane = tid & 63, w = tid >> 6;
  int wm = w >> 2, wn = w & 3;                 // 2 row-waves x 4 col-waves
  int quad = lane >> 4, l15 = lane & 15;
  __shared__ float Ered[4][128];               // 4 col-wave partials per row
  __shared__ float Ecol[2][128];               // 2 row-wave partials per col

  size_t uA[4], uB[2];
#pragma unroll
  for (int f = 0; f < 4; f++)
    uA[f] = ((size_t)(img * NGRP + it * 8 + wm * 4 + f) * 16) * 64 + lane;
#pragma unroll
  for (int f = 0; f < 2; f++)
    uB[f] = ((size_t)(img * NGRP + jt * 8 + wn * 2 + f) * 16) * 64 + lane;

  v4f acc[4][2];
#pragma unroll
  for (int mf = 0; mf < 4; mf++)
#pragma unroll
    for (int nf = 0; nf < 2; nf++) acc[mf][nf] = (v4f){0.f, 0.f, 0.f, 0.f};

  v8s a0[4], b0[2], a1[4], b1[2];
#define LOADG(kc, AR, BR)                                               \
  {                                                                     \
    _Pragma("unroll") for (int f = 0; f < 4; f++)                       \
        AR[f] = *(const v8s*)(bfemb4 + uA[f] + (kc) * 64);              \
    _Pragma("unroll") for (int f = 0; f < 2; f++)                       \
        BR[f] = *(const v8s*)(bfemb4 + uB[f] + (kc) * 64);              \
  }
#define MFMAG(AR, BR)                                                   \
  {                                                                     \
    _Pragma("unroll") for (int mf = 0; mf < 4; mf++)                    \
        _Pragma("unroll") for (int nf = 0; nf < 2; nf++)                \
            acc[mf][nf] = __builtin_amdgcn_mfma_f32_16x16x32_bf16(      \
                AR[mf], BR[nf], acc[mf][nf], 0, 0, 0);                  \
  }

  LOADG(0, a0, b0);
#pragma unroll
  for (int kc = 0; kc < 16; kc += 2) {
    if (kc + 1 < 16) LOADG(kc + 1, a1, b1);
    MFMAG(a0, b0);
    if (kc + 2 < 16) LOADG(kc + 2, a0, b0);
    MFMAG(a1, b1);
  }
#undef LOADG
#undef MFMAG

  // epilogue: C/D layout col = lane&15, row = quad*4 + reg; rn2 == 1.
  float scol[2] = {0.f, 0.f};
#pragma unroll
  for (int mf = 0; mf < 4; mf++) {
#pragma unroll
    for (int rr = 0; rr < 4; rr++) {
      int i = i0 + wm * 64 + mf * 16 + quad * 4 + rr;
      float srow = 0.f;
#pragma unroll
      for (int nf = 0; nf < 2; nf++) {
        int j = j0 + wn * 32 + nf * 16 + l15;
        float e = __expf((acc[mf][nf][rr] - 1.f) * INVT);
        bool ok = (j < NPIX) && (!diag || (i != j && i < NPIX));
        e = ok ? e : 0.f;
        srow += e;
        scol[nf] += e;
      }
      srow += __shfl_xor(srow, 1); srow += __shfl_xor(srow, 2);
      srow += __shfl_xor(srow, 4); srow += __shfl_xor(srow, 8);
      if (l15 == 0) Ered[wn][wm * 64 + mf * 16 + quad * 4 + rr] = srow;
    }
  }
  if (!diag) {
#pragma unroll
    for (int nf = 0; nf < 2; nf++) {
      float s = scol[nf];
      s += __shfl_xor(s, 16); s += __shfl_xor(s, 32);
      if (quad == 0) Ecol[wm][wn * 32 + nf * 16 + l15] = s;
    }
  }
  __syncthreads();
  if (tid < 128) {
    E9[((size_t)img * NT9 + jt) * NROWPAD + i0 + tid] =
        Ered[0][tid] + Ered[1][tid] + Ered[2][tid] + Ered[3][tid];
    if (!diag)
      E9[((size_t)img * NT9 + it) * NROWPAD + j0 + tid] = Ecol[0][tid] + Ecol[1][tid];
  }
}

// ---- K3: per-image losses + ticket-fused cross-image aggregation (512 threads) ----
__global__ __launch_bounds__(512) void k_imgfinal(const float* __restrict__ sums9,
                                                  const int* __restrict__ labels,
                                                  const float* __restrict__ cnt9,
                                                  const float* __restrict__ E9,
                                                  const float* __restrict__ is_forged,
                                                  unsigned* __restrict__ counter,
                                                  float* __restrict__ per_img,
                                                  float* __restrict__ out) {
  int b = blockIdx.x, tid = threadIdx.x;
  int wave = tid >> 6, lane = tid & 63;
  __shared__ float ssum[NLBL * DIM];  // 16 KB reduced per-label sums
  __shared__ float sCnt[NLBL], sR[NLBL][NLBL];
  __shared__ float sLog, sNA;
  if (tid < NLBL) {
    float s = 0.f;
#pragma unroll
    for (int g = 0; g < NT9; g++) s += cnt9[((size_t)b * NT9 + g) * NLBL + tid];
    sCnt[tid] = s;
  }
  if (tid == 0) { sLog = 0.f; sNA = 0.f; }
  for (int o = tid; o < NLBL * DIM; o += 512) {
    float s = 0.f;
#pragma unroll
    for (int g = 0; g < NT9; g++) s += sums9[((size_t)(b * NT9 + g) * NLBL * DIM) + o];
    ssum[o] = s;
  }
  __syncthreads();
  float ll = 0.f, na = 0.f;
  for (int p = tid; p < NPIX; p += 512) {
    int lab = labels[b * NROWPAD + p];
    if (sCnt[lab] >= 1.5f) {
      float e = 0.f;
#pragma unroll
      for (int s = 0; s < NT9; s++) e += E9[((size_t)b * NT9 + s) * NROWPAD + p];
      ll += __logf(e + 1e-6f);
      na += 1.f;
    }
  }
  ll = wave_reduce(ll); na = wave_reduce(na);
  if (lane == 0) { atomicAdd(&sLog, ll); atomicAdd(&sNA, na); }
  for (int t = wave; t < 36; t += 8) {
    int a = 0, tt = t;
    while (tt >= NLBL - a) { tt -= NLBL - a; a++; }
    int bb = a + tt;
    float d0 = 0.f;
    for (int k = lane; k < DIM; k += 64) d0 += ssum[a * DIM + k] * ssum[bb * DIM + k];
    d0 = wave_reduce(d0);
    if (lane == 0) sR[a][bb] = d0;
  }
  __syncthreads();
  if (tid == 0) {
    float spos = 0.f;
    for (int l = 0; l < NLBL; l++) {
      float c = sCnt[l];
      if (c >= 1.5f) spos += (sR[l][l] - c) * INVT / (c - 1.f) - c * INVT;
    }
    float nA = sNA;
    float sc = nA > 0.f ? (sLog - spos) / nA : 0.f;
    float scv = nA > 0.f ? 1.f : 0.f;
    float inv[NLBL]; int present[NLBL]; int nPres = 0;
    for (int l = 0; l < NLBL; l++) {
      present[l] = sCnt[l] > 0.f;
      nPres += present[l];
      inv[l] = 1.f / fmaxf(sCnt[l], 1.f);
    }
    float sepsum = 0.f; int npairs = 0;
    for (int a = 0; a < NLBL; a++)
      for (int c = a + 1; c < NLBL; c++)
        if (present[a] && present[c]) {
          float sq_ = sR[a][a] * inv[a] * inv[a] + sR[c][c] * inv[c] * inv[c]
                    - 2.f * sR[a][c] * inv[a] * inv[c];
          float dd = sqrtf(fmaxf(sq_, 0.f));
          sepsum += fmaxf(2.f - dd, 0.f);
          npairs++;
        }
    float sep = npairs > 0 ? sepsum / (float)npairs : 0.f;
    float sepv = nPres >= 2 ? 1.f : 0.f;
    float inst = 0.f; int nlbl = 0;
    for (int l = 0; l < NLBL; l++) {
      float var = 1.f - sR[l][l] * inv[l] * inv[l];  // q_l/c = 1
      if (sCnt[l] >= 2.f && var > 0.1f) { inst += var - 0.1f; nlbl++; }
    }
    float unif = nlbl > 0 ? inst / (float)nlbl : 0.f;
    float unifv = nlbl > 0 ? 1.f : 0.f;
    float tot2 = 0.f;
    for (int a = 0; a < NLBL; a++) {
      tot2 += sR[a][a];
      for (int c = a + 1; c < NLBL; c++) tot2 += 2.f * sR[a][c];
    }
    float Nf = (float)NPIX;
    float var_all = 1.f - tot2 / (Nf * Nf);  // totq/N = 1
    float uniu = var_all > 0.1f ? var_all - 0.1f : 0.f;
    float uniuv = var_all > 0.1f ? 1.f : 0.f;
    bool isf = is_forged[b] >= 0.5f;
    per_img[b * 6 + 0] = sc;
    per_img[b * 6 + 1] = scv;
    per_img[b * 6 + 2] = sep;
    per_img[b * 6 + 3] = sepv;
    per_img[b * 6 + 4] = isf ? unif : uniu;
    per_img[b * 6 + 5] = isf ? unifv : uniuv;
    __threadfence();  // release per_img before the ticket
    unsigned tk = atomicAdd(counter, 1u);
    if (tk == NIMG - 1) {  // last block aggregates
      __threadfence();
      float accv[3] = {0.f, 0.f, 0.f}, accn[3] = {0.f, 0.f, 0.f};
      for (int bb = 0; bb < NIMG; bb++)
        for (int m = 0; m < 3; m++) {
          float v = per_img[bb * 6 + m * 2], val = per_img[bb * 6 + m * 2 + 1];
          accv[m] += v * val; accn[m] += val;
        }
      float scA = accn[0] > 0.f ? accv[0] / accn[0] : 0.f;
      float sepA = accn[1] > 0.f ? accv[1] / accn[1] : 0.f;
      float uniA = accn[2] > 0.f ? accv[2] / accn[2] : 0.f;
      out[0] = 1.0f * scA + 0.5f * sepA + 0.5f * uniA;
    }
  }
}

extern "C" void kernel_launch(void* const* d_in, const int* in_sizes, int n_in,
                              void* d_out, int out_size, void* d_ws, size_t ws_size,
                              hipStream_t stream) {
  const float* emb = (const float*)d_in[0];
  const float* masks = (const float*)d_in[1];
  const float* isf = (const float*)d_in[2];
  float* out = (float*)d_out;
  char* ws = (char*)d_ws;
  size_t off = 0;
  uint4* bfemb4 = (uint4*)(ws + off);
  off += (size_t)NIMG * NGRP * 16 * 64 * 16;                      // 18.9 MB fragment-ordered bf16
  float* E9 = (float*)(ws + off);     off += sizeof(float) * NIMG * NT9 * NROWPAD;    // 663 KB
  float* sums9 = (float*)(ws + off);  off += sizeof(float) * NIMG * NT9 * NLBL * DIM; // 2.36 MB
  int* labels = (int*)(ws + off);     off += sizeof(int) * NIMG * NROWPAD;
  float* cnt9 = (float*)(ws + off);   off += sizeof(float) * NIMG * NT9 * NLBL;
  float* per_img = (float*)(ws + off); off += sizeof(float) * NIMG * 6;
  off = (off + 127) & ~(size_t)127;
  unsigned* counter = (unsigned*)(ws + off); off += 128;

  // 3 launches; no memset (owner-writes only; ticket zeroed by k_packsum)
  k_packsum<<<dim3(18, NIMG), 512, 0, stream>>>(emb, masks, (uint2*)bfemb4, sums9,
                                                labels, cnt9, counter);
  k_epass5<<<45 * NIMG, 512, 0, stream>>>(bfemb4, E9);
  k_imgfinal<<<NIMG, 512, 0, stream>>>(sums9, labels, cnt9, E9, isf, counter, per_img, out);
}